// Round 1
// baseline (698.755 us; speedup 1.0000x reference)
//
#include <hip/hip_runtime.h>

#define NN 50000
#define NE 800000
#define DD 128
#define NL 3
#define BN_EPS 1e-5f

// ---------------- CSR build ----------------

__global__ void hist_kernel(const int* __restrict__ dst, int* __restrict__ counts) {
    int e = blockIdx.x * 256 + threadIdx.x;
    if (e < NE) atomicAdd(&counts[dst[e]], 1);
}

__global__ void scan1_kernel(const int* __restrict__ counts, int* __restrict__ otmp,
                             int* __restrict__ bsums) {
    __shared__ int sd[1024];
    int t = threadIdx.x;
    int i = blockIdx.x * 1024 + t;
    int v = (i < NN) ? counts[i] : 0;
    sd[t] = v; __syncthreads();
    for (int off = 1; off < 1024; off <<= 1) {
        int tmp = (t >= off) ? sd[t - off] : 0;
        __syncthreads();
        sd[t] += tmp;
        __syncthreads();
    }
    if (i < NN) otmp[i] = sd[t] - v;   // exclusive within block
    if (t == 1023) bsums[blockIdx.x] = sd[1023];
}

__global__ void scan2_kernel(const int* __restrict__ bsums, int* __restrict__ boffs, int nb) {
    __shared__ int sd[64];
    int t = threadIdx.x;
    int v = (t < nb) ? bsums[t] : 0;
    sd[t] = v; __syncthreads();
    for (int off = 1; off < 64; off <<= 1) {
        int tmp = (t >= off) ? sd[t - off] : 0;
        __syncthreads();
        sd[t] += tmp;
        __syncthreads();
    }
    if (t < nb) boffs[t] = sd[t] - v;  // exclusive
}

__global__ void scan3_kernel(const int* __restrict__ otmp, const int* __restrict__ boffs,
                             int* __restrict__ offsets) {
    int i = blockIdx.x * 1024 + threadIdx.x;
    if (i < NN) offsets[i] = otmp[i] + boffs[blockIdx.x];
}

__global__ void fill_kernel(const int* __restrict__ src, const int* __restrict__ dst,
                            const int* __restrict__ offsets, int* __restrict__ cursor,
                            int* __restrict__ csr) {
    int e = blockIdx.x * 256 + threadIdx.x;
    if (e < NE) {
        int d = dst[e];
        int pos = offsets[d] + atomicAdd(&cursor[d], 1);
        csr[pos] = src[e];
    }
}

// ---------------- aggregation: one wave per node ----------------

__global__ void agg_kernel(const float* __restrict__ h, const int* __restrict__ offsets,
                           const int* __restrict__ counts, const int* __restrict__ csr,
                           const float* __restrict__ eps, int l, float* __restrict__ agg) {
    int wid = (int)((blockIdx.x * blockDim.x + threadIdx.x) >> 6);
    int lane = threadIdx.x & 63;
    if (wid >= NN) return;
    float se = 1.0f + eps[l];
    const float2* hp = (const float2*)(h + (size_t)wid * DD);
    float2 acc = hp[lane];
    acc.x *= se; acc.y *= se;
    int start = offsets[wid];
    int cnt = counts[wid];
    for (int e = 0; e < cnt; ++e) {
        int s = csr[start + e];
        const float2* sp = (const float2*)(h + (size_t)s * DD);
        float2 v = sp[lane];
        acc.x += v.x; acc.y += v.y;
    }
    ((float2*)(agg + (size_t)wid * DD))[lane] = acc;
}

// ---------------- fused GEMM (A[N,128] @ W[128,128]) + epilogue ----------------
// mode 0: +bias, BN(eval), ReLU   (first MLP linear)
// mode 1: +bias, ReLU             (second linear, inter-layer)
// mode 2: +bias                   (second linear, last layer)

__device__ __forceinline__ void load_chunk(float (&a)[4][8], const float* __restrict__ A,
                                           int r0, int kc) {
#pragma unroll
    for (int i = 0; i < 4; ++i) {
        int r = r0 + i;
        if (r < NN) {
            const float4* p = (const float4*)(A + (size_t)r * DD + kc * 8);
            float4 v0 = p[0], v1 = p[1];
            a[i][0] = v0.x; a[i][1] = v0.y; a[i][2] = v0.z; a[i][3] = v0.w;
            a[i][4] = v1.x; a[i][5] = v1.y; a[i][6] = v1.z; a[i][7] = v1.w;
        } else {
#pragma unroll
            for (int j = 0; j < 8; ++j) a[i][j] = 0.0f;
        }
    }
}

__device__ __forceinline__ void fma_chunk(float (&acc)[4][8], const float (&a)[4][8],
                                          const float* wl, int kc, int c0) {
#pragma unroll
    for (int kk = 0; kk < 8; ++kk) {
        int k = kc * 8 + kk;
        const float4* wp = (const float4*)(wl + k * DD + c0);
        float4 w0 = wp[0], w1 = wp[1];
        float wv[8] = {w0.x, w0.y, w0.z, w0.w, w1.x, w1.y, w1.z, w1.w};
#pragma unroll
        for (int i = 0; i < 4; ++i)
#pragma unroll
            for (int j = 0; j < 8; ++j)
                acc[i][j] = fmaf(a[i][kk], wv[j], acc[i][j]);
    }
}

__global__ __launch_bounds__(256) void gemm_fused_kernel(
    const float* __restrict__ A, const float* __restrict__ W,
    const float* __restrict__ bias, const float* __restrict__ gamma,
    const float* __restrict__ beta, const float* __restrict__ mean,
    const float* __restrict__ var, float* __restrict__ out, int mode) {
    __shared__ float wl[DD * DD];  // 64 KB
    int t = threadIdx.x;
    {
        const float4* W4 = (const float4*)W;
        float4* wl4 = (float4*)wl;
#pragma unroll
        for (int i = 0; i < 16; ++i) wl4[i * 256 + t] = W4[i * 256 + t];
    }
    __syncthreads();

    int tc = t & 15, tr = t >> 4;
    int r0 = blockIdx.x * 64 + tr * 4;
    int c0 = tc * 8;

    float acc[4][8] = {};
    float aA[4][8], aB[4][8];
    load_chunk(aA, A, r0, 0);
#pragma unroll 1
    for (int kc = 0; kc < 16; kc += 2) {
        load_chunk(aB, A, r0, kc + 1);
        fma_chunk(acc, aA, wl, kc, c0);
        if (kc + 2 < 16) load_chunk(aA, A, r0, kc + 2);
        fma_chunk(acc, aB, wl, kc + 1, c0);
    }

    // epilogue params per column
    float bs[8], scale[8], shift[8];
#pragma unroll
    for (int j = 0; j < 8; ++j) bs[j] = bias[c0 + j];
    if (mode == 0) {
#pragma unroll
        for (int j = 0; j < 8; ++j) {
            float iv = rsqrtf(var[c0 + j] + BN_EPS);
            scale[j] = iv * gamma[c0 + j];
            shift[j] = beta[c0 + j] - mean[c0 + j] * scale[j];
        }
    }

#pragma unroll
    for (int i = 0; i < 4; ++i) {
        int r = r0 + i;
        if (r >= NN) continue;
        float v[8];
#pragma unroll
        for (int j = 0; j < 8; ++j) {
            float x = acc[i][j] + bs[j];
            if (mode == 0) x = fmaxf(x * scale[j] + shift[j], 0.0f);
            else if (mode == 1) x = fmaxf(x, 0.0f);
            v[j] = x;
        }
        float4* op = (float4*)(out + (size_t)r * DD + c0);
        op[0] = make_float4(v[0], v[1], v[2], v[3]);
        op[1] = make_float4(v[4], v[5], v[6], v[7]);
    }
}

// ---------------- launch ----------------

extern "C" void kernel_launch(void* const* d_in, const int* in_sizes, int n_in,
                              void* d_out, int out_size, void* d_ws, size_t ws_size,
                              hipStream_t stream) {
    const float* x     = (const float*)d_in[0];
    const int*   eidx  = (const int*)d_in[1];   // [2, E]
    const float* W1    = (const float*)d_in[2];
    const float* b1    = (const float*)d_in[3];
    const float* gamma = (const float*)d_in[4];
    const float* beta  = (const float*)d_in[5];
    const float* bnm   = (const float*)d_in[6];
    const float* bnv   = (const float*)d_in[7];
    const float* W2    = (const float*)d_in[8];
    const float* b2    = (const float*)d_in[9];
    const float* eps   = (const float*)d_in[10];
    float* out = (float*)d_out;

    const int* src = eidx;
    const int* dst = eidx + NE;

    char* w = (char*)d_ws;
    float* bufA = (float*)w;           w += (size_t)NN * DD * 4;
    float* bufB = (float*)w;           w += (size_t)NN * DD * 4;
    int* csr    = (int*)w;             w += (size_t)NE * 4;
    int* counts = (int*)w;             w += (size_t)NN * 4;
    int* offs   = (int*)w;             w += (size_t)NN * 4;
    int* cursor = (int*)w;             w += (size_t)NN * 4;
    int* bsums  = (int*)w;             w += 64 * 4;
    int* boffs  = (int*)w;             w += 64 * 4;

    hipMemsetAsync(counts, 0, (size_t)NN * 4, stream);
    hipMemsetAsync(cursor, 0, (size_t)NN * 4, stream);

    int nbScan = (NN + 1023) / 1024;  // 49
    hist_kernel<<<(NE + 255) / 256, 256, 0, stream>>>(dst, counts);
    scan1_kernel<<<nbScan, 1024, 0, stream>>>(counts, offs /*tmp in-place? no*/, bsums);
    // note: scan1 writes exclusive-in-block into offs (used as otmp), then scan3 adds block offsets in-place
    scan2_kernel<<<1, 64, 0, stream>>>(bsums, boffs, nbScan);
    scan3_kernel<<<nbScan, 1024, 0, stream>>>(offs, boffs, offs);
    fill_kernel<<<(NE + 255) / 256, 256, 0, stream>>>(src, dst, offs, cursor, csr);

    const float* hin[NL]   = {x, bufA, bufB};
    float* aggbuf[NL]      = {bufA, bufB, bufA};
    float* g1out[NL]       = {bufB, bufA, bufB};
    float* g2out[NL]       = {bufA, bufB, out};

    int aggBlocks = (NN * 64 + 255) / 256;       // 4 nodes (waves) per block
    int gemmBlocks = (NN + 63) / 64;             // 782

    for (int l = 0; l < NL; ++l) {
        agg_kernel<<<aggBlocks, 256, 0, stream>>>(hin[l], offs, counts, csr, eps, l, aggbuf[l]);
        gemm_fused_kernel<<<gemmBlocks, 256, 0, stream>>>(
            aggbuf[l], W1 + (size_t)l * DD * DD, b1 + (size_t)l * DD,
            gamma + (size_t)l * DD, beta + (size_t)l * DD,
            bnm + (size_t)l * DD, bnv + (size_t)l * DD, g1out[l], 0);
        gemm_fused_kernel<<<gemmBlocks, 256, 0, stream>>>(
            g1out[l], W2 + (size_t)l * DD * DD, b2 + (size_t)l * DD,
            nullptr, nullptr, nullptr, nullptr, g2out[l], (l < NL - 1) ? 1 : 2);
    }
}

// Round 2
// 487.131 us; speedup vs baseline: 1.4344x; 1.4344x over previous
//
#include <hip/hip_runtime.h>

#define NN 50000
#define NE 800000
#define DD 128
#define NL 3
#define BN_EPS 1e-5f

typedef short bf16x8 __attribute__((ext_vector_type(8)));
typedef float f32x4  __attribute__((ext_vector_type(4)));
typedef unsigned int u32x4 __attribute__((ext_vector_type(4)));

// ---- hi/lo bf16 packing: p = (hi<<16) | lo, value = f(hi) + f(lo) ≈ fp32 ----

__device__ __forceinline__ unsigned int rne16(float v) {
    unsigned int u = __float_as_uint(v);
    return (u + 0x7fffu + ((u >> 16) & 1u)) >> 16;
}
__device__ __forceinline__ unsigned int packf(float v) {
    unsigned int hb = rne16(v);
    float hf = __uint_as_float(hb << 16);
    unsigned int lb = rne16(v - hf);
    return (hb << 16) | lb;
}
__device__ __forceinline__ float unpackf(unsigned int p) {
    return __uint_as_float(p & 0xffff0000u) + __uint_as_float(p << 16);
}

// ---------------- CSR build ----------------

__global__ void hist_kernel(const int* __restrict__ dst, int* __restrict__ counts) {
    int e = blockIdx.x * 256 + threadIdx.x;
    if (e < NE) atomicAdd(&counts[dst[e]], 1);
}

__global__ void scan1_kernel(const int* __restrict__ counts, int* __restrict__ otmp,
                             int* __restrict__ bsums) {
    __shared__ int sd[1024];
    int t = threadIdx.x;
    int i = blockIdx.x * 1024 + t;
    int v = (i < NN) ? counts[i] : 0;
    sd[t] = v; __syncthreads();
    for (int off = 1; off < 1024; off <<= 1) {
        int tmp = (t >= off) ? sd[t - off] : 0;
        __syncthreads();
        sd[t] += tmp;
        __syncthreads();
    }
    if (i < NN) otmp[i] = sd[t] - v;
    if (t == 1023) bsums[blockIdx.x] = sd[1023];
}

__global__ void scan2_kernel(const int* __restrict__ bsums, int* __restrict__ boffs, int nb) {
    __shared__ int sd[64];
    int t = threadIdx.x;
    int v = (t < nb) ? bsums[t] : 0;
    sd[t] = v; __syncthreads();
    for (int off = 1; off < 64; off <<= 1) {
        int tmp = (t >= off) ? sd[t - off] : 0;
        __syncthreads();
        sd[t] += tmp;
        __syncthreads();
    }
    if (t < nb) boffs[t] = sd[t] - v;
}

__global__ void scan3_kernel(const int* __restrict__ otmp, const int* __restrict__ boffs,
                             int* __restrict__ offsets) {
    int i = blockIdx.x * 1024 + threadIdx.x;
    if (i < NN) offsets[i] = otmp[i] + boffs[blockIdx.x];
}

__global__ void fill_kernel(const int* __restrict__ src, const int* __restrict__ dst,
                            const int* __restrict__ offsets, int* __restrict__ cursor,
                            int* __restrict__ csr) {
    int e = blockIdx.x * 256 + threadIdx.x;
    if (e < NE) {
        int d = dst[e];
        int pos = offsets[d] + atomicAdd(&cursor[d], 1);
        csr[pos] = src[e];
    }
}

// ---------------- W split: fp32 [k][n] -> transposed bf16 hi/lo [n][k] ----------------
// matrices 0..2 = W1 layers, 3..5 = W2 layers

__global__ void wsplit_kernel(const float* __restrict__ W1, const float* __restrict__ W2,
                              unsigned short* __restrict__ Whi, unsigned short* __restrict__ Wlo) {
    int idx = blockIdx.x * 256 + threadIdx.x;   // 0 .. 6*16384-1
    if (idx >= 6 * 16384) return;
    int m = idx >> 14;
    int r = idx & 16383;
    int n = r >> 7, k = r & 127;
    const float* Wsrc = (m < 3) ? (W1 + (size_t)m * 16384) : (W2 + (size_t)(m - 3) * 16384);
    float v = Wsrc[k * DD + n];
    unsigned int hb = rne16(v);
    float hf = __uint_as_float(hb << 16);
    unsigned int lb = rne16(v - hf);
    Whi[idx] = (unsigned short)hb;
    Wlo[idx] = (unsigned short)lb;
}

// ---------------- aggregation: one wave per node, unroll-4 gather ----------------

template <bool PACKED>
__global__ __launch_bounds__(256) void agg_kernel(const void* __restrict__ hv,
    const int* __restrict__ offsets, const int* __restrict__ counts,
    const int* __restrict__ csr, const float* __restrict__ eps, int l,
    unsigned int* __restrict__ aggp) {
    int wid = (int)((blockIdx.x * 256 + threadIdx.x) >> 6);
    int lane = threadIdx.x & 63;
    if (wid >= NN) return;
    float se = 1.0f + eps[l];
    float ax, ay;
    if (PACKED) {
        uint2 s = ((const uint2*)((const unsigned int*)hv + (size_t)wid * DD))[lane];
        ax = unpackf(s.x) * se; ay = unpackf(s.y) * se;
    } else {
        float2 s = ((const float2*)((const float*)hv + (size_t)wid * DD))[lane];
        ax = s.x * se; ay = s.y * se;
    }
    int e = offsets[wid];
    int end = e + counts[wid];
    for (; e + 4 <= end; e += 4) {
        int s0 = csr[e], s1 = csr[e + 1], s2 = csr[e + 2], s3 = csr[e + 3];
        if (PACKED) {
            const unsigned int* h = (const unsigned int*)hv;
            uint2 p0 = ((const uint2*)(h + (size_t)s0 * DD))[lane];
            uint2 p1 = ((const uint2*)(h + (size_t)s1 * DD))[lane];
            uint2 p2 = ((const uint2*)(h + (size_t)s2 * DD))[lane];
            uint2 p3 = ((const uint2*)(h + (size_t)s3 * DD))[lane];
            ax += unpackf(p0.x) + unpackf(p1.x) + unpackf(p2.x) + unpackf(p3.x);
            ay += unpackf(p0.y) + unpackf(p1.y) + unpackf(p2.y) + unpackf(p3.y);
        } else {
            const float* h = (const float*)hv;
            float2 p0 = ((const float2*)(h + (size_t)s0 * DD))[lane];
            float2 p1 = ((const float2*)(h + (size_t)s1 * DD))[lane];
            float2 p2 = ((const float2*)(h + (size_t)s2 * DD))[lane];
            float2 p3 = ((const float2*)(h + (size_t)s3 * DD))[lane];
            ax += p0.x + p1.x + p2.x + p3.x;
            ay += p0.y + p1.y + p2.y + p3.y;
        }
    }
    for (; e < end; ++e) {
        int s0 = csr[e];
        if (PACKED) {
            uint2 p0 = ((const uint2*)((const unsigned int*)hv + (size_t)s0 * DD))[lane];
            ax += unpackf(p0.x); ay += unpackf(p0.y);
        } else {
            float2 p0 = ((const float2*)((const float*)hv + (size_t)s0 * DD))[lane];
            ax += p0.x; ay += p0.y;
        }
    }
    uint2 o; o.x = packf(ax); o.y = packf(ay);
    ((uint2*)(aggp + (size_t)wid * DD))[lane] = o;
}

// ---------------- MFMA GEMM: A(packed hi/lo)[N,128] @ W[128,128], split product ----------------
// mode 0: +b1, BN(eval), ReLU -> packed
// mode 1: +b2, ReLU -> packed
// mode 2: +b2 -> fp32 out

__global__ __launch_bounds__(256) void gemm_kernel(
    const unsigned int* __restrict__ Ap, const unsigned short* __restrict__ Whi,
    const unsigned short* __restrict__ Wlo, const float* __restrict__ bias,
    const float* __restrict__ gamma, const float* __restrict__ beta,
    const float* __restrict__ mean, const float* __restrict__ var,
    void* __restrict__ outp, int mode) {
    __shared__ unsigned int Al[64 * DD];   // 32 KB, chunk-XOR swizzled
    int t = threadIdx.x;
    int lane = t & 63, w = t >> 6;
    int r0 = blockIdx.x * 64;
    int cb = w * 32;

    // W fragments in registers: [kb][nb] hi/lo. B-frag lane l: n = l&15, k = (l>>4)*8 + j
    bf16x8 wh[4][2], wl[4][2];
#pragma unroll
    for (int kb = 0; kb < 4; ++kb)
#pragma unroll
        for (int nb = 0; nb < 2; ++nb) {
            int n = cb + nb * 16 + (lane & 15);
            int k = kb * 32 + ((lane >> 4) << 3);
            wh[kb][nb] = *(const bf16x8*)(Whi + (size_t)n * DD + k);
            wl[kb][nb] = *(const bf16x8*)(Wlo + (size_t)n * DD + k);
        }

    // stage A tile (64 rows x 128 uint32) into LDS, 16B-chunk XOR swizzle by (row&7)
    {
        int cchunk = t & 31;
#pragma unroll
        for (int it = 0; it < 8; ++it) {
            int rl = it * 8 + (t >> 5);
            int rg = r0 + rl; if (rg > NN - 1) rg = NN - 1;
            u32x4 v = *(const u32x4*)(Ap + (size_t)rg * DD + cchunk * 4);
            int c = cchunk ^ (rl & 7);
            *(u32x4*)(&Al[rl * DD + c * 4]) = v;
        }
    }
    __syncthreads();

    f32x4 acc[4][2];
#pragma unroll
    for (int r = 0; r < 4; ++r)
#pragma unroll
        for (int nb = 0; nb < 2; ++nb) acc[r][nb] = (f32x4){0.f, 0.f, 0.f, 0.f};

#pragma unroll
    for (int r = 0; r < 4; ++r) {
        int rl = r * 16 + (lane & 15);
        int sw = rl & 7;
#pragma unroll
        for (int kb = 0; kb < 4; ++kb) {
            int c0 = kb * 8 + ((lane >> 4) << 1);
            u32x4 q0 = *(const u32x4*)(&Al[rl * DD + (c0 ^ sw) * 4]);
            u32x4 q1 = *(const u32x4*)(&Al[rl * DD + ((c0 + 1) ^ sw) * 4]);
            u32x4 hr, lr;
            hr.x = (q0.x >> 16) | (q0.y & 0xffff0000u);
            hr.y = (q0.z >> 16) | (q0.w & 0xffff0000u);
            hr.z = (q1.x >> 16) | (q1.y & 0xffff0000u);
            hr.w = (q1.z >> 16) | (q1.w & 0xffff0000u);
            lr.x = (q0.x & 0xffffu) | (q0.y << 16);
            lr.y = (q0.z & 0xffffu) | (q0.w << 16);
            lr.z = (q1.x & 0xffffu) | (q1.y << 16);
            lr.w = (q1.z & 0xffffu) | (q1.w << 16);
            bf16x8 ah = __builtin_bit_cast(bf16x8, hr);
            bf16x8 al = __builtin_bit_cast(bf16x8, lr);
#pragma unroll
            for (int nb = 0; nb < 2; ++nb) {
                acc[r][nb] = __builtin_amdgcn_mfma_f32_16x16x32_bf16(ah, wh[kb][nb], acc[r][nb], 0, 0, 0);
                acc[r][nb] = __builtin_amdgcn_mfma_f32_16x16x32_bf16(ah, wl[kb][nb], acc[r][nb], 0, 0, 0);
                acc[r][nb] = __builtin_amdgcn_mfma_f32_16x16x32_bf16(al, wh[kb][nb], acc[r][nb], 0, 0, 0);
            }
        }
    }

    // epilogue. C/D layout: col = lane&15, row = (lane>>4)*4 + j
#pragma unroll
    for (int nb = 0; nb < 2; ++nb) {
        int col = cb + nb * 16 + (lane & 15);
        float bs = bias[col];
        float sc = 1.0f, sh = 0.0f;
        if (mode == 0) {
            float iv = rsqrtf(var[col] + BN_EPS);
            sc = iv * gamma[col];
            sh = beta[col] - mean[col] * sc;
        }
#pragma unroll
        for (int r = 0; r < 4; ++r) {
#pragma unroll
            for (int j = 0; j < 4; ++j) {
                int orow = r0 + r * 16 + ((lane >> 4) << 2) + j;
                if (orow < NN) {
                    float v = acc[r][nb][j] + bs;
                    if (mode == 0) v = fmaxf(fmaf(v, sc, sh), 0.0f);
                    else if (mode == 1) v = fmaxf(v, 0.0f);
                    if (mode == 2) ((float*)outp)[(size_t)orow * DD + col] = v;
                    else ((unsigned int*)outp)[(size_t)orow * DD + col] = packf(v);
                }
            }
        }
    }
}

// ---------------- launch ----------------

extern "C" void kernel_launch(void* const* d_in, const int* in_sizes, int n_in,
                              void* d_out, int out_size, void* d_ws, size_t ws_size,
                              hipStream_t stream) {
    const float* x     = (const float*)d_in[0];
    const int*   eidx  = (const int*)d_in[1];
    const float* W1    = (const float*)d_in[2];
    const float* b1    = (const float*)d_in[3];
    const float* gamma = (const float*)d_in[4];
    const float* beta  = (const float*)d_in[5];
    const float* bnm   = (const float*)d_in[6];
    const float* bnv   = (const float*)d_in[7];
    const float* W2    = (const float*)d_in[8];
    const float* b2    = (const float*)d_in[9];
    const float* eps   = (const float*)d_in[10];
    float* out = (float*)d_out;

    const int* src = eidx;
    const int* dst = eidx + NE;

    char* wsp = (char*)d_ws;
    unsigned int* bufA = (unsigned int*)wsp;  wsp += (size_t)NN * DD * 4;
    unsigned int* bufB = (unsigned int*)wsp;  wsp += (size_t)NN * DD * 4;
    int* csr    = (int*)wsp;                  wsp += (size_t)NE * 4;
    int* counts = (int*)wsp;                  wsp += (size_t)NN * 4;
    int* offs   = (int*)wsp;                  wsp += (size_t)NN * 4;
    int* cursor = (int*)wsp;                  wsp += (size_t)NN * 4;
    unsigned short* Whi = (unsigned short*)wsp; wsp += (size_t)6 * 16384 * 2;
    unsigned short* Wlo = (unsigned short*)wsp; wsp += (size_t)6 * 16384 * 2;
    int* bsums  = (int*)wsp;                  wsp += 64 * 4;
    int* boffs  = (int*)wsp;                  wsp += 64 * 4;

    hipMemsetAsync(counts, 0, (size_t)NN * 4, stream);
    hipMemsetAsync(cursor, 0, (size_t)NN * 4, stream);

    int nbScan = (NN + 1023) / 1024;
    hist_kernel<<<(NE + 255) / 256, 256, 0, stream>>>(dst, counts);
    scan1_kernel<<<nbScan, 1024, 0, stream>>>(counts, offs, bsums);
    scan2_kernel<<<1, 64, 0, stream>>>(bsums, boffs, nbScan);
    scan3_kernel<<<nbScan, 1024, 0, stream>>>(offs, boffs, offs);
    fill_kernel<<<(NE + 255) / 256, 256, 0, stream>>>(src, dst, offs, cursor, csr);
    wsplit_kernel<<<(6 * 16384 + 255) / 256, 256, 0, stream>>>(W1, W2, Whi, Wlo);

    int aggBlocks = (NN * 64 + 255) / 256;
    int gemmBlocks = (NN + 63) / 64;

    // L0: agg x->A, g1 A->B (W1[0]), g2 B->A (W2[0])
    // L1: agg A->B, g1 B->A (W1[1]), g2 A->B (W2[1])
    // L2: agg B->A, g1 A->B (W1[2]), g2 B->out (W2[2])
    unsigned int* aggIn[NL]  = {nullptr, bufA, bufB};
    unsigned int* aggOut[NL] = {bufA, bufB, bufA};
    unsigned int* g1Out[NL]  = {bufB, bufA, bufB};
    void* g2Out[NL]          = {bufA, bufB, out};

    for (int l = 0; l < NL; ++l) {
        if (l == 0)
            agg_kernel<false><<<aggBlocks, 256, 0, stream>>>(x, offs, counts, csr, eps, l, aggOut[l]);
        else
            agg_kernel<true><<<aggBlocks, 256, 0, stream>>>(aggIn[l], offs, counts, csr, eps, l, aggOut[l]);
        gemm_kernel<<<gemmBlocks, 256, 0, stream>>>(
            aggOut[l], Whi + (size_t)l * 16384, Wlo + (size_t)l * 16384,
            b1 + (size_t)l * DD, gamma + (size_t)l * DD, beta + (size_t)l * DD,
            bnm + (size_t)l * DD, bnv + (size_t)l * DD, g1Out[l], 0);
        gemm_kernel<<<gemmBlocks, 256, 0, stream>>>(
            g1Out[l], Whi + (size_t)(3 + l) * 16384, Wlo + (size_t)(3 + l) * 16384,
            b2 + (size_t)l * DD, nullptr, nullptr, nullptr, nullptr,
            g2Out[l], (l < NL - 1) ? 1 : 2);
    }
}

// Round 3
// 460.651 us; speedup vs baseline: 1.5169x; 1.0575x over previous
//
#include <hip/hip_runtime.h>

#define NN 50000
#define NE 800000
#define DD 128
#define NL 3
#define BN_EPS 1e-5f

typedef short bf16x8 __attribute__((ext_vector_type(8)));
typedef float f32x4  __attribute__((ext_vector_type(4)));
typedef unsigned int u32x4 __attribute__((ext_vector_type(4)));

// ---- hi/lo bf16 packing: p = (hi<<16) | lo, value = f(hi) + f(lo) ≈ fp32 ----

__device__ __forceinline__ unsigned int rne16(float v) {
    unsigned int u = __float_as_uint(v);
    return (u + 0x7fffu + ((u >> 16) & 1u)) >> 16;
}
__device__ __forceinline__ unsigned int packf(float v) {
    unsigned int hb = rne16(v);
    float hf = __uint_as_float(hb << 16);
    unsigned int lb = rne16(v - hf);
    return (hb << 16) | lb;
}
__device__ __forceinline__ float unpackf(unsigned int p) {
    return __uint_as_float(p & 0xffff0000u) + __uint_as_float(p << 16);
}

// ---------------- CSR build ----------------

__global__ void hist_kernel(const int* __restrict__ dst, int* __restrict__ counts) {
    int e = blockIdx.x * 256 + threadIdx.x;
    if (e < NE) atomicAdd(&counts[dst[e]], 1);
}

__global__ void scan1_kernel(const int* __restrict__ counts, int* __restrict__ otmp,
                             int* __restrict__ bsums) {
    __shared__ int sd[1024];
    int t = threadIdx.x;
    int i = blockIdx.x * 1024 + t;
    int v = (i < NN) ? counts[i] : 0;
    sd[t] = v; __syncthreads();
    for (int off = 1; off < 1024; off <<= 1) {
        int tmp = (t >= off) ? sd[t - off] : 0;
        __syncthreads();
        sd[t] += tmp;
        __syncthreads();
    }
    if (i < NN) otmp[i] = sd[t] - v;
    if (t == 1023) bsums[blockIdx.x] = sd[1023];
}

__global__ void scan2_kernel(const int* __restrict__ bsums, int* __restrict__ boffs, int nb) {
    __shared__ int sd[64];
    int t = threadIdx.x;
    int v = (t < nb) ? bsums[t] : 0;
    sd[t] = v; __syncthreads();
    for (int off = 1; off < 64; off <<= 1) {
        int tmp = (t >= off) ? sd[t - off] : 0;
        __syncthreads();
        sd[t] += tmp;
        __syncthreads();
    }
    if (t < nb) boffs[t] = sd[t] - v;
}

__global__ void scan3_kernel(const int* __restrict__ otmp, const int* __restrict__ boffs,
                             int* __restrict__ offsets) {
    int i = blockIdx.x * 1024 + threadIdx.x;
    if (i < NN) offsets[i] = otmp[i] + boffs[blockIdx.x];
}

__global__ void fill_kernel(const int* __restrict__ src, const int* __restrict__ dst,
                            const int* __restrict__ offsets, int* __restrict__ cursor,
                            int* __restrict__ csr) {
    int e = blockIdx.x * 256 + threadIdx.x;
    if (e < NE) {
        int d = dst[e];
        int pos = offsets[d] + atomicAdd(&cursor[d], 1);
        csr[pos] = src[e];
    }
}

// ---------------- W split: fp32 [k][n] -> transposed bf16 hi/lo [n][k] ----------------

__global__ void wsplit_kernel(const float* __restrict__ W1, const float* __restrict__ W2,
                              unsigned short* __restrict__ Whi, unsigned short* __restrict__ Wlo) {
    int idx = blockIdx.x * 256 + threadIdx.x;
    if (idx >= 6 * 16384) return;
    int m = idx >> 14;
    int r = idx & 16383;
    int n = r >> 7, k = r & 127;
    const float* Wsrc = (m < 3) ? (W1 + (size_t)m * 16384) : (W2 + (size_t)(m - 3) * 16384);
    float v = Wsrc[k * DD + n];
    unsigned int hb = rne16(v);
    float hf = __uint_as_float(hb << 16);
    unsigned int lb = rne16(v - hf);
    Whi[idx] = (unsigned short)hb;
    Wlo[idx] = (unsigned short)lb;
}

// ---------------- aggregation: one wave per node, unroll-8 gather ----------------

template <bool PACKED>
__global__ __launch_bounds__(256) void agg_kernel(const void* __restrict__ hv,
    const int* __restrict__ offsets, const int* __restrict__ counts,
    const int* __restrict__ csr, const float* __restrict__ eps, int l,
    unsigned int* __restrict__ aggp) {
    int wid = (int)((blockIdx.x * 256 + threadIdx.x) >> 6);
    int lane = threadIdx.x & 63;
    if (wid >= NN) return;
    float se = 1.0f + eps[l];
    float ax, ay;
    if (PACKED) {
        uint2 s = ((const uint2*)((const unsigned int*)hv + (size_t)wid * DD))[lane];
        ax = unpackf(s.x) * se; ay = unpackf(s.y) * se;
    } else {
        float2 s = ((const float2*)((const float*)hv + (size_t)wid * DD))[lane];
        ax = s.x * se; ay = s.y * se;
    }
    int e = offsets[wid];
    int end = e + counts[wid];
    for (; e + 8 <= end; e += 8) {
        int idx[8];
#pragma unroll
        for (int q = 0; q < 8; ++q) idx[q] = csr[e + q];
        if (PACKED) {
            const unsigned int* h = (const unsigned int*)hv;
            uint2 p[8];
#pragma unroll
            for (int q = 0; q < 8; ++q) p[q] = ((const uint2*)(h + (size_t)idx[q] * DD))[lane];
#pragma unroll
            for (int q = 0; q < 8; ++q) { ax += unpackf(p[q].x); ay += unpackf(p[q].y); }
        } else {
            const float* h = (const float*)hv;
            float2 p[8];
#pragma unroll
            for (int q = 0; q < 8; ++q) p[q] = ((const float2*)(h + (size_t)idx[q] * DD))[lane];
#pragma unroll
            for (int q = 0; q < 8; ++q) { ax += p[q].x; ay += p[q].y; }
        }
    }
    for (; e + 2 <= end; e += 2) {
        int s0 = csr[e], s1 = csr[e + 1];
        if (PACKED) {
            const unsigned int* h = (const unsigned int*)hv;
            uint2 p0 = ((const uint2*)(h + (size_t)s0 * DD))[lane];
            uint2 p1 = ((const uint2*)(h + (size_t)s1 * DD))[lane];
            ax += unpackf(p0.x) + unpackf(p1.x);
            ay += unpackf(p0.y) + unpackf(p1.y);
        } else {
            const float* h = (const float*)hv;
            float2 p0 = ((const float2*)(h + (size_t)s0 * DD))[lane];
            float2 p1 = ((const float2*)(h + (size_t)s1 * DD))[lane];
            ax += p0.x + p1.x;
            ay += p0.y + p1.y;
        }
    }
    for (; e < end; ++e) {
        int s0 = csr[e];
        if (PACKED) {
            uint2 p0 = ((const uint2*)((const unsigned int*)hv + (size_t)s0 * DD))[lane];
            ax += unpackf(p0.x); ay += unpackf(p0.y);
        } else {
            float2 p0 = ((const float2*)((const float*)hv + (size_t)s0 * DD))[lane];
            ax += p0.x; ay += p0.y;
        }
    }
    uint2 o; o.x = packf(ax); o.y = packf(ay);
    ((uint2*)(aggp + (size_t)wid * DD))[lane] = o;
}

// ---------------- fused MLP: GEMM1 + BN + ReLU + GEMM2 (+ReLU / fp32 out) ----------------
// A packed hi/lo [N,128]; W* transposed bf16 [n][k]; z1 kept in LDS.

__device__ __forceinline__ void gemm_half(const unsigned int* Al, const bf16x8 (&wh)[4][2],
                                          const bf16x8 (&wl)[4][2], int lane,
                                          f32x4 (&acc)[4][2]) {
#pragma unroll
    for (int r = 0; r < 4; ++r) {
        int rl = r * 16 + (lane & 15);
        int sw = rl & 7;
#pragma unroll
        for (int kb = 0; kb < 4; ++kb) {
            int c0 = kb * 8 + ((lane >> 4) << 1);
            u32x4 q0 = *(const u32x4*)(&Al[rl * DD + ((c0 ^ sw) << 2)]);
            u32x4 q1 = *(const u32x4*)(&Al[rl * DD + (((c0 + 1) ^ sw) << 2)]);
            u32x4 hr, lr;
            hr.x = (q0.x >> 16) | (q0.y & 0xffff0000u);
            hr.y = (q0.z >> 16) | (q0.w & 0xffff0000u);
            hr.z = (q1.x >> 16) | (q1.y & 0xffff0000u);
            hr.w = (q1.z >> 16) | (q1.w & 0xffff0000u);
            lr.x = (q0.x & 0xffffu) | (q0.y << 16);
            lr.y = (q0.z & 0xffffu) | (q0.w << 16);
            lr.z = (q1.x & 0xffffu) | (q1.y << 16);
            lr.w = (q1.z & 0xffffu) | (q1.w << 16);
            bf16x8 ah = __builtin_bit_cast(bf16x8, hr);
            bf16x8 al = __builtin_bit_cast(bf16x8, lr);
#pragma unroll
            for (int nb = 0; nb < 2; ++nb) {
                acc[r][nb] = __builtin_amdgcn_mfma_f32_16x16x32_bf16(ah, wh[kb][nb], acc[r][nb], 0, 0, 0);
                acc[r][nb] = __builtin_amdgcn_mfma_f32_16x16x32_bf16(ah, wl[kb][nb], acc[r][nb], 0, 0, 0);
                acc[r][nb] = __builtin_amdgcn_mfma_f32_16x16x32_bf16(al, wh[kb][nb], acc[r][nb], 0, 0, 0);
            }
        }
    }
}

__global__ __launch_bounds__(256) void mlp_kernel(
    const unsigned int* __restrict__ Ap,
    const unsigned short* __restrict__ Wh1, const unsigned short* __restrict__ Wl1,
    const unsigned short* __restrict__ Wh2, const unsigned short* __restrict__ Wl2,
    const float* __restrict__ b1v, const float* __restrict__ gamma,
    const float* __restrict__ beta, const float* __restrict__ mean,
    const float* __restrict__ var, const float* __restrict__ b2v,
    void* __restrict__ outp, int last) {
    __shared__ unsigned int Al[64 * DD];   // 32 KB; holds A, then z1
    int t = threadIdx.x;
    int lane = t & 63, w = t >> 6;
    int r0 = blockIdx.x * 64;
    int cb = w * 32;
    int nfrag = lane & 15;
    int kfrag = (lane >> 4) << 3;

    // W1 fragments
    bf16x8 wh1[4][2], wl1[4][2];
#pragma unroll
    for (int kb = 0; kb < 4; ++kb)
#pragma unroll
        for (int nb = 0; nb < 2; ++nb) {
            size_t off = (size_t)(cb + nb * 16 + nfrag) * DD + kb * 32 + kfrag;
            wh1[kb][nb] = *(const bf16x8*)(Wh1 + off);
            wl1[kb][nb] = *(const bf16x8*)(Wl1 + off);
        }

    // stage A tile (64 rows x 128 u32), 16B-chunk XOR swizzle by (row&7)
    {
        int cchunk = t & 31;
#pragma unroll
        for (int it = 0; it < 8; ++it) {
            int rl = it * 8 + (t >> 5);
            int rg = r0 + rl; if (rg > NN - 1) rg = NN - 1;
            u32x4 v = *(const u32x4*)(Ap + (size_t)rg * DD + cchunk * 4);
            *(u32x4*)(&Al[rl * DD + ((cchunk ^ (rl & 7)) << 2)]) = v;
        }
    }
    __syncthreads();

    f32x4 acc[4][2];
#pragma unroll
    for (int r = 0; r < 4; ++r)
#pragma unroll
        for (int nb = 0; nb < 2; ++nb) acc[r][nb] = (f32x4){0.f, 0.f, 0.f, 0.f};

    gemm_half(Al, wh1, wl1, lane, acc);

    // W2 fragments (global, L2-hot; latency hides under epilogue)
    bf16x8 wh2[4][2], wl2[4][2];
#pragma unroll
    for (int kb = 0; kb < 4; ++kb)
#pragma unroll
        for (int nb = 0; nb < 2; ++nb) {
            size_t off = (size_t)(cb + nb * 16 + nfrag) * DD + kb * 32 + kfrag;
            wh2[kb][nb] = *(const bf16x8*)(Wh2 + off);
            wl2[kb][nb] = *(const bf16x8*)(Wl2 + off);
        }

    __syncthreads();   // WAR: all Al reads done before z1 overwrite

    // epilogue1: bias+BN+ReLU, pack, write z1 into Al (same swizzle scheme)
#pragma unroll
    for (int nb = 0; nb < 2; ++nb) {
        int col = cb + nb * 16 + nfrag;
        float bs = b1v[col];
        float iv = rsqrtf(var[col] + BN_EPS);
        float sc = iv * gamma[col];
        float sh = beta[col] - mean[col] * sc;
#pragma unroll
        for (int r = 0; r < 4; ++r)
#pragma unroll
            for (int j = 0; j < 4; ++j) {
                int row = r * 16 + ((lane >> 4) << 2) + j;
                float v = fmaxf(fmaf(acc[r][nb][j] + bs, sc, sh), 0.0f);
                Al[row * DD + ((((col >> 2) ^ (row & 7)) << 2) | (col & 3))] = packf(v);
            }
    }
    __syncthreads();

#pragma unroll
    for (int r = 0; r < 4; ++r)
#pragma unroll
        for (int nb = 0; nb < 2; ++nb) acc[r][nb] = (f32x4){0.f, 0.f, 0.f, 0.f};

    gemm_half(Al, wh2, wl2, lane, acc);

    // epilogue2: bias (+ReLU+pack | fp32 store)
#pragma unroll
    for (int nb = 0; nb < 2; ++nb) {
        int col = cb + nb * 16 + nfrag;
        float bs = b2v[col];
#pragma unroll
        for (int r = 0; r < 4; ++r)
#pragma unroll
            for (int j = 0; j < 4; ++j) {
                int orow = r0 + r * 16 + ((lane >> 4) << 2) + j;
                if (orow < NN) {
                    float v = acc[r][nb][j] + bs;
                    if (last) {
                        ((float*)outp)[(size_t)orow * DD + col] = v;
                    } else {
                        ((unsigned int*)outp)[(size_t)orow * DD + col] = packf(fmaxf(v, 0.0f));
                    }
                }
            }
    }
}

// ---------------- launch ----------------

extern "C" void kernel_launch(void* const* d_in, const int* in_sizes, int n_in,
                              void* d_out, int out_size, void* d_ws, size_t ws_size,
                              hipStream_t stream) {
    const float* x     = (const float*)d_in[0];
    const int*   eidx  = (const int*)d_in[1];
    const float* W1    = (const float*)d_in[2];
    const float* b1    = (const float*)d_in[3];
    const float* gamma = (const float*)d_in[4];
    const float* beta  = (const float*)d_in[5];
    const float* bnm   = (const float*)d_in[6];
    const float* bnv   = (const float*)d_in[7];
    const float* W2    = (const float*)d_in[8];
    const float* b2    = (const float*)d_in[9];
    const float* eps   = (const float*)d_in[10];
    float* out = (float*)d_out;

    const int* src = eidx;
    const int* dst = eidx + NE;

    char* wsp = (char*)d_ws;
    unsigned int* bufA = (unsigned int*)wsp;  wsp += (size_t)NN * DD * 4;
    unsigned int* bufB = (unsigned int*)wsp;  wsp += (size_t)NN * DD * 4;
    int* csr    = (int*)wsp;                  wsp += (size_t)NE * 4;
    int* counts = (int*)wsp;                  wsp += (size_t)NN * 4;
    int* offs   = (int*)wsp;                  wsp += (size_t)NN * 4;
    int* cursor = (int*)wsp;                  wsp += (size_t)NN * 4;
    unsigned short* Whi = (unsigned short*)wsp; wsp += (size_t)6 * 16384 * 2;
    unsigned short* Wlo = (unsigned short*)wsp; wsp += (size_t)6 * 16384 * 2;
    int* bsums  = (int*)wsp;                  wsp += 64 * 4;
    int* boffs  = (int*)wsp;                  wsp += 64 * 4;

    hipMemsetAsync(counts, 0, (size_t)NN * 4, stream);
    hipMemsetAsync(cursor, 0, (size_t)NN * 4, stream);

    int nbScan = (NN + 1023) / 1024;
    hist_kernel<<<(NE + 255) / 256, 256, 0, stream>>>(dst, counts);
    wsplit_kernel<<<(6 * 16384 + 255) / 256, 256, 0, stream>>>(W1, W2, Whi, Wlo);
    scan1_kernel<<<nbScan, 1024, 0, stream>>>(counts, offs, bsums);
    scan2_kernel<<<1, 64, 0, stream>>>(bsums, boffs, nbScan);
    scan3_kernel<<<nbScan, 1024, 0, stream>>>(offs, boffs, offs);
    fill_kernel<<<(NE + 255) / 256, 256, 0, stream>>>(src, dst, offs, cursor, csr);

    int aggBlocks = (NN * 64 + 255) / 256;
    int gemmBlocks = (NN + 63) / 64;

    unsigned int* aggIn[NL]  = {nullptr, bufB, bufA};
    unsigned int* aggOut[NL] = {bufA, bufA, bufA};
    void* mlpOut[NL]         = {bufB, bufA, out};
    // L0: agg x->bufA,  mlp bufA->bufB
    // L1: agg bufB->bufA, mlp bufA->bufA? NO -- need distinct in/out
    // fix ping-pong below

    // correct ping-pong:
    // L0: agg x    -> bufA ; mlp bufA -> bufB
    // L1: agg bufB -> bufA ; mlp bufA -> bufB
    // L2: agg bufB -> bufA ; mlp bufA -> out
    for (int l = 0; l < NL; ++l) {
        if (l == 0)
            agg_kernel<false><<<aggBlocks, 256, 0, stream>>>(x, offs, counts, csr, eps, l, bufA);
        else
            agg_kernel<true><<<aggBlocks, 256, 0, stream>>>(bufB, offs, counts, csr, eps, l, bufA);
        mlp_kernel<<<gemmBlocks, 256, 0, stream>>>(
            bufA,
            Whi + (size_t)l * 16384, Wlo + (size_t)l * 16384,
            Whi + (size_t)(3 + l) * 16384, Wlo + (size_t)(3 + l) * 16384,
            b1 + (size_t)l * DD, gamma + (size_t)l * DD, beta + (size_t)l * DD,
            bnm + (size_t)l * DD, bnv + (size_t)l * DD, b2 + (size_t)l * DD,
            (l == NL - 1) ? (void*)out : (void*)bufB, (l == NL - 1) ? 1 : 0);
    }
}

// Round 4
// 419.761 us; speedup vs baseline: 1.6646x; 1.0974x over previous
//
#include <hip/hip_runtime.h>
#include <hip/hip_fp16.h>

#define NN 50000
#define NE 800000
#define DD 128
#define NL 3
#define BN_EPS 1e-5f

typedef short bf16x8 __attribute__((ext_vector_type(8)));
typedef float f32x4  __attribute__((ext_vector_type(4)));
typedef unsigned int u32x4 __attribute__((ext_vector_type(4)));

// ---- hi/lo bf16 packing: p = (hi<<16) | lo, value = f(hi) + f(lo) ≈ fp32 ----

__device__ __forceinline__ unsigned int rne16(float v) {
    unsigned int u = __float_as_uint(v);
    return (u + 0x7fffu + ((u >> 16) & 1u)) >> 16;
}
__device__ __forceinline__ unsigned int packf(float v) {
    unsigned int hb = rne16(v);
    float hf = __uint_as_float(hb << 16);
    unsigned int lb = rne16(v - hf);
    return (hb << 16) | lb;
}
__device__ __forceinline__ float unpackf(unsigned int p) {
    return __uint_as_float(p & 0xffff0000u) + __uint_as_float(p << 16);
}

// ---------------- CSR build (4 edges/thread for ILP) ----------------

#define ET (NE / 4)   // 200000 threads, 4 strided edges each

__global__ void hist_kernel(const int* __restrict__ dst, int* __restrict__ counts) {
    int t = blockIdx.x * 256 + threadIdx.x;
    if (t >= ET) return;
    int d0 = dst[t], d1 = dst[t + ET], d2 = dst[t + 2 * ET], d3 = dst[t + 3 * ET];
    atomicAdd(&counts[d0], 1);
    atomicAdd(&counts[d1], 1);
    atomicAdd(&counts[d2], 1);
    atomicAdd(&counts[d3], 1);
}

__global__ void scan1_kernel(const int* __restrict__ counts, int* __restrict__ otmp,
                             int* __restrict__ bsums) {
    __shared__ int sd[1024];
    int t = threadIdx.x;
    int i = blockIdx.x * 1024 + t;
    int v = (i < NN) ? counts[i] : 0;
    sd[t] = v; __syncthreads();
    for (int off = 1; off < 1024; off <<= 1) {
        int tmp = (t >= off) ? sd[t - off] : 0;
        __syncthreads();
        sd[t] += tmp;
        __syncthreads();
    }
    if (i < NN) otmp[i] = sd[t] - v;
    if (t == 1023) bsums[blockIdx.x] = sd[1023];
}

__global__ void scan2_kernel(const int* __restrict__ bsums, int* __restrict__ boffs, int nb) {
    __shared__ int sd[64];
    int t = threadIdx.x;
    int v = (t < nb) ? bsums[t] : 0;
    sd[t] = v; __syncthreads();
    for (int off = 1; off < 64; off <<= 1) {
        int tmp = (t >= off) ? sd[t - off] : 0;
        __syncthreads();
        sd[t] += tmp;
        __syncthreads();
    }
    if (t < nb) boffs[t] = sd[t] - v;
}

__global__ void scan3_kernel(const int* __restrict__ otmp, const int* __restrict__ boffs,
                             int* __restrict__ offsets) {
    int i = blockIdx.x * 1024 + threadIdx.x;
    if (i < NN) offsets[i] = otmp[i] + boffs[blockIdx.x];
}

__global__ void fill_kernel(const int* __restrict__ src, const int* __restrict__ dst,
                            const int* __restrict__ offsets, int* __restrict__ cursor,
                            int* __restrict__ csr) {
    int t = blockIdx.x * 256 + threadIdx.x;
    if (t >= ET) return;
    int d[4], s[4], p[4];
#pragma unroll
    for (int q = 0; q < 4; ++q) {
        d[q] = dst[t + q * ET];
        s[q] = src[t + q * ET];
    }
#pragma unroll
    for (int q = 0; q < 4; ++q)
        p[q] = offsets[d[q]] + atomicAdd(&cursor[d[q]], 1);
#pragma unroll
    for (int q = 0; q < 4; ++q)
        csr[p[q]] = s[q];
}

// ---------------- W split: fp32 [k][n] -> transposed bf16 hi/lo [n][k] ----------------

__global__ void wsplit_kernel(const float* __restrict__ W1, const float* __restrict__ W2,
                              unsigned short* __restrict__ Whi, unsigned short* __restrict__ Wlo) {
    int idx = blockIdx.x * 256 + threadIdx.x;
    if (idx >= 6 * 16384) return;
    int m = idx >> 14;
    int r = idx & 16383;
    int n = r >> 7, k = r & 127;
    const float* Wsrc = (m < 3) ? (W1 + (size_t)m * 16384) : (W2 + (size_t)(m - 3) * 16384);
    float v = Wsrc[k * DD + n];
    unsigned int hb = rne16(v);
    float hf = __uint_as_float(hb << 16);
    unsigned int lb = rne16(v - hf);
    Whi[idx] = (unsigned short)hb;
    Wlo[idx] = (unsigned short)lb;
}

// ---------------- x -> fp16 copy ----------------

__global__ void tofp16_kernel(const float* __restrict__ x, unsigned int* __restrict__ x16) {
    int i = blockIdx.x * 256 + threadIdx.x;   // over NN*64 float2s
    if (i >= NN * 64) return;
    float2 v = ((const float2*)x)[i];
    __half2 h = __float22half2_rn(v);
    x16[i] = __builtin_bit_cast(unsigned int, h);
}

// ---------------- aggregation: one wave per node; fp16 neighbor gather ----------------
// self term full precision (fp32 for layer 0, packed hi/lo after)

template <bool SELF_F32>
__global__ __launch_bounds__(256) void agg_kernel(const void* __restrict__ selfv,
    const unsigned int* __restrict__ h16,
    const int* __restrict__ offsets, const int* __restrict__ counts,
    const int* __restrict__ csr, const float* __restrict__ eps, int l,
    unsigned int* __restrict__ aggp) {
    int wid = (int)((blockIdx.x * 256 + threadIdx.x) >> 6);
    int lane = threadIdx.x & 63;
    if (wid >= NN) return;
    float se = 1.0f + eps[l];
    float ax, ay;
    if (SELF_F32) {
        float2 s = ((const float2*)((const float*)selfv + (size_t)wid * DD))[lane];
        ax = s.x * se; ay = s.y * se;
    } else {
        uint2 s = ((const uint2*)((const unsigned int*)selfv + (size_t)wid * DD))[lane];
        ax = unpackf(s.x) * se; ay = unpackf(s.y) * se;
    }
    int e = offsets[wid];
    int end = e + counts[wid];
    for (; e + 8 <= end; e += 8) {
        int idx[8];
#pragma unroll
        for (int q = 0; q < 8; ++q) idx[q] = csr[e + q];
        unsigned int p[8];
#pragma unroll
        for (int q = 0; q < 8; ++q) p[q] = h16[(size_t)idx[q] * 64 + lane];
#pragma unroll
        for (int q = 0; q < 8; ++q) {
            float2 f = __half22float2(__builtin_bit_cast(__half2, p[q]));
            ax += f.x; ay += f.y;
        }
    }
    for (; e < end; ++e) {
        unsigned int p = h16[(size_t)csr[e] * 64 + lane];
        float2 f = __half22float2(__builtin_bit_cast(__half2, p));
        ax += f.x; ay += f.y;
    }
    uint2 o; o.x = packf(ax); o.y = packf(ay);
    ((uint2*)(aggp + (size_t)wid * DD))[lane] = o;
}

// ---------------- fused MLP: GEMM1 + BN + ReLU + GEMM2 (+ReLU / fp32 out) ----------------

__device__ __forceinline__ void gemm_half(const unsigned int* Al, const bf16x8 (&wh)[4][2],
                                          const bf16x8 (&wl)[4][2], int lane,
                                          f32x4 (&acc)[4][2]) {
#pragma unroll
    for (int r = 0; r < 4; ++r) {
        int rl = r * 16 + (lane & 15);
        int sw = rl & 7;
#pragma unroll
        for (int kb = 0; kb < 4; ++kb) {
            int c0 = kb * 8 + ((lane >> 4) << 1);
            u32x4 q0 = *(const u32x4*)(&Al[rl * DD + ((c0 ^ sw) << 2)]);
            u32x4 q1 = *(const u32x4*)(&Al[rl * DD + (((c0 + 1) ^ sw) << 2)]);
            u32x4 hr, lr;
            hr.x = (q0.x >> 16) | (q0.y & 0xffff0000u);
            hr.y = (q0.z >> 16) | (q0.w & 0xffff0000u);
            hr.z = (q1.x >> 16) | (q1.y & 0xffff0000u);
            hr.w = (q1.z >> 16) | (q1.w & 0xffff0000u);
            lr.x = (q0.x & 0xffffu) | (q0.y << 16);
            lr.y = (q0.z & 0xffffu) | (q0.w << 16);
            lr.z = (q1.x & 0xffffu) | (q1.y << 16);
            lr.w = (q1.z & 0xffffu) | (q1.w << 16);
            bf16x8 ah = __builtin_bit_cast(bf16x8, hr);
            bf16x8 al = __builtin_bit_cast(bf16x8, lr);
#pragma unroll
            for (int nb = 0; nb < 2; ++nb) {
                acc[r][nb] = __builtin_amdgcn_mfma_f32_16x16x32_bf16(ah, wh[kb][nb], acc[r][nb], 0, 0, 0);
                acc[r][nb] = __builtin_amdgcn_mfma_f32_16x16x32_bf16(ah, wl[kb][nb], acc[r][nb], 0, 0, 0);
                acc[r][nb] = __builtin_amdgcn_mfma_f32_16x16x32_bf16(al, wh[kb][nb], acc[r][nb], 0, 0, 0);
            }
        }
    }
}

__global__ __launch_bounds__(256, 3) void mlp_kernel(
    const unsigned int* __restrict__ Ap,
    const unsigned short* __restrict__ Wh1, const unsigned short* __restrict__ Wl1,
    const unsigned short* __restrict__ Wh2, const unsigned short* __restrict__ Wl2,
    const float* __restrict__ b1v, const float* __restrict__ gamma,
    const float* __restrict__ beta, const float* __restrict__ mean,
    const float* __restrict__ var, const float* __restrict__ b2v,
    void* __restrict__ outp, unsigned short* __restrict__ out16, int last) {
    __shared__ unsigned int Al[64 * DD];   // 32 KB; holds A, then z1
    int t = threadIdx.x;
    int lane = t & 63, w = t >> 6;
    int r0 = blockIdx.x * 64;
    int cb = w * 32;
    int nfrag = lane & 15;
    int kfrag = (lane >> 4) << 3;

    // W1 fragments (reused for W2 after gemm1 to halve W register footprint)
    bf16x8 wh[4][2], wl[4][2];
#pragma unroll
    for (int kb = 0; kb < 4; ++kb)
#pragma unroll
        for (int nb = 0; nb < 2; ++nb) {
            size_t off = (size_t)(cb + nb * 16 + nfrag) * DD + kb * 32 + kfrag;
            wh[kb][nb] = *(const bf16x8*)(Wh1 + off);
            wl[kb][nb] = *(const bf16x8*)(Wl1 + off);
        }

    // stage A tile (64 rows x 128 u32), 16B-chunk XOR swizzle by (row&7)
    {
        int cchunk = t & 31;
#pragma unroll
        for (int it = 0; it < 8; ++it) {
            int rl = it * 8 + (t >> 5);
            int rg = r0 + rl; if (rg > NN - 1) rg = NN - 1;
            u32x4 v = *(const u32x4*)(Ap + (size_t)rg * DD + cchunk * 4);
            *(u32x4*)(&Al[rl * DD + ((cchunk ^ (rl & 7)) << 2)]) = v;
        }
    }
    __syncthreads();

    f32x4 acc[4][2];
#pragma unroll
    for (int r = 0; r < 4; ++r)
#pragma unroll
        for (int nb = 0; nb < 2; ++nb) acc[r][nb] = (f32x4){0.f, 0.f, 0.f, 0.f};

    gemm_half(Al, wh, wl, lane, acc);

    // W2 fragments into the SAME registers (W1 dead); latency hides under epilogue1
#pragma unroll
    for (int kb = 0; kb < 4; ++kb)
#pragma unroll
        for (int nb = 0; nb < 2; ++nb) {
            size_t off = (size_t)(cb + nb * 16 + nfrag) * DD + kb * 32 + kfrag;
            wh[kb][nb] = *(const bf16x8*)(Wh2 + off);
            wl[kb][nb] = *(const bf16x8*)(Wl2 + off);
        }

    __syncthreads();   // WAR: all Al reads done before z1 overwrite

    // epilogue1: bias+BN+ReLU, pack, write z1 into Al (same swizzle scheme)
#pragma unroll
    for (int nb = 0; nb < 2; ++nb) {
        int col = cb + nb * 16 + nfrag;
        float bs = b1v[col];
        float iv = rsqrtf(var[col] + BN_EPS);
        float sc = iv * gamma[col];
        float sh = beta[col] - mean[col] * sc;
#pragma unroll
        for (int r = 0; r < 4; ++r)
#pragma unroll
            for (int j = 0; j < 4; ++j) {
                int row = r * 16 + ((lane >> 4) << 2) + j;
                float v = fmaxf(fmaf(acc[r][nb][j] + bs, sc, sh), 0.0f);
                Al[row * DD + ((((col >> 2) ^ (row & 7)) << 2) | (col & 3))] = packf(v);
            }
    }
    __syncthreads();

#pragma unroll
    for (int r = 0; r < 4; ++r)
#pragma unroll
        for (int nb = 0; nb < 2; ++nb) acc[r][nb] = (f32x4){0.f, 0.f, 0.f, 0.f};

    gemm_half(Al, wh, wl, lane, acc);

    // epilogue2: bias (+ReLU -> packed + fp16 | fp32 store)
#pragma unroll
    for (int nb = 0; nb < 2; ++nb) {
        int col = cb + nb * 16 + nfrag;
        float bs = b2v[col];
#pragma unroll
        for (int r = 0; r < 4; ++r)
#pragma unroll
            for (int j = 0; j < 4; ++j) {
                int orow = r0 + r * 16 + ((lane >> 4) << 2) + j;
                if (orow < NN) {
                    float v = acc[r][nb][j] + bs;
                    if (last) {
                        ((float*)outp)[(size_t)orow * DD + col] = v;
                    } else {
                        v = fmaxf(v, 0.0f);
                        ((unsigned int*)outp)[(size_t)orow * DD + col] = packf(v);
                        out16[(size_t)orow * DD + col] =
                            __builtin_bit_cast(unsigned short, __float2half_rn(v));
                    }
                }
            }
    }
}

// ---------------- launch ----------------

extern "C" void kernel_launch(void* const* d_in, const int* in_sizes, int n_in,
                              void* d_out, int out_size, void* d_ws, size_t ws_size,
                              hipStream_t stream) {
    const float* x     = (const float*)d_in[0];
    const int*   eidx  = (const int*)d_in[1];
    const float* W1    = (const float*)d_in[2];
    const float* b1    = (const float*)d_in[3];
    const float* gamma = (const float*)d_in[4];
    const float* beta  = (const float*)d_in[5];
    const float* bnm   = (const float*)d_in[6];
    const float* bnv   = (const float*)d_in[7];
    const float* W2    = (const float*)d_in[8];
    const float* b2    = (const float*)d_in[9];
    const float* eps   = (const float*)d_in[10];
    float* out = (float*)d_out;

    const int* src = eidx;
    const int* dst = eidx + NE;

    char* wsp = (char*)d_ws;
    unsigned int* bufA = (unsigned int*)wsp;  wsp += (size_t)NN * DD * 4;
    unsigned int* bufB = (unsigned int*)wsp;  wsp += (size_t)NN * DD * 4;
    unsigned int* x16  = (unsigned int*)wsp;  wsp += (size_t)NN * DD * 2;
    unsigned int* h16  = (unsigned int*)wsp;  wsp += (size_t)NN * DD * 2;
    int* csr    = (int*)wsp;                  wsp += (size_t)NE * 4;
    int* counts = (int*)wsp;                  wsp += (size_t)NN * 4;
    int* offs   = (int*)wsp;                  wsp += (size_t)NN * 4;
    int* cursor = (int*)wsp;                  wsp += (size_t)NN * 4;
    unsigned short* Whi = (unsigned short*)wsp; wsp += (size_t)6 * 16384 * 2;
    unsigned short* Wlo = (unsigned short*)wsp; wsp += (size_t)6 * 16384 * 2;
    int* bsums  = (int*)wsp;                  wsp += 64 * 4;
    int* boffs  = (int*)wsp;                  wsp += 64 * 4;

    hipMemsetAsync(counts, 0, (size_t)NN * 4, stream);
    hipMemsetAsync(cursor, 0, (size_t)NN * 4, stream);

    int nbScan = (NN + 1023) / 1024;
    hist_kernel<<<(ET + 255) / 256, 256, 0, stream>>>(dst, counts);
    wsplit_kernel<<<(6 * 16384 + 255) / 256, 256, 0, stream>>>(W1, W2, Whi, Wlo);
    tofp16_kernel<<<(NN * 64 + 255) / 256, 256, 0, stream>>>(x, x16);
    scan1_kernel<<<nbScan, 1024, 0, stream>>>(counts, offs, bsums);
    scan2_kernel<<<1, 64, 0, stream>>>(bsums, boffs, nbScan);
    scan3_kernel<<<nbScan, 1024, 0, stream>>>(offs, boffs, offs);
    fill_kernel<<<(ET + 255) / 256, 256, 0, stream>>>(src, dst, offs, cursor, csr);

    int aggBlocks = (NN * 64 + 255) / 256;
    int gemmBlocks = (NN + 63) / 64;

    // L0: agg(x fp32 self, x16 nbr)   -> bufA ; mlp bufA -> bufB + h16
    // L1: agg(bufB self, h16 nbr)     -> bufA ; mlp bufA -> bufB + h16
    // L2: agg(bufB self, h16 nbr)     -> bufA ; mlp bufA -> out (fp32)
    for (int l = 0; l < NL; ++l) {
        if (l == 0)
            agg_kernel<true><<<aggBlocks, 256, 0, stream>>>(x, x16, offs, counts, csr, eps, l, bufA);
        else
            agg_kernel<false><<<aggBlocks, 256, 0, stream>>>(bufB, h16, offs, counts, csr, eps, l, bufA);
        int last = (l == NL - 1);
        mlp_kernel<<<gemmBlocks, 256, 0, stream>>>(
            bufA,
            Whi + (size_t)l * 16384, Wlo + (size_t)l * 16384,
            Whi + (size_t)(3 + l) * 16384, Wlo + (size_t)(3 + l) * 16384,
            b1 + (size_t)l * DD, gamma + (size_t)l * DD, beta + (size_t)l * DD,
            bnm + (size_t)l * DD, bnv + (size_t)l * DD, b2 + (size_t)l * DD,
            last ? (void*)out : (void*)bufB, (unsigned short*)h16, last);
    }
}